// Round 4
// baseline (7722.015 us; speedup 1.0000x reference)
//
#include <hip/hip_runtime.h>

#define N_PTS 32768
#define HID   100
#define STEPS 100

// Output layout (concatenated flat, fp32):
#define OFF_Z     0
#define OFF_MUXZ  65536
#define OFF_LSXZ  163840
#define OFF_MUZX  262144
#define OFF_LTZX  327680
#define OFF_MUZ   360448
#define OFF_LTZ   425984

typedef float v2f __attribute__((ext_vector_type(2)));

#if __has_builtin(__builtin_elementwise_fma)
#define FMA2(a, b, c) __builtin_elementwise_fma((a), (b), (c))
#else
#define FMA2(a, b, c) ((a) * (b) + (c))
#endif

__device__ __forceinline__ v2f splat(float x) { v2f r; r.x = x; r.y = x; return r; }

// Butterfly sum across a quad of lanes via DPP quad_perm (xor1=0xB1, xor2=0x4E).
__device__ __forceinline__ float qreduce(float v) {
  v += __int_as_float(__builtin_amdgcn_update_dpp(0, __float_as_int(v), 0xB1, 0xF, 0xF, true));
  v += __int_as_float(__builtin_amdgcn_update_dpp(0, __float_as_int(v), 0x4E, 0xF, 0xF, true));
  return v;
}

// ---------------- Encoder: x -> h1 -> h2 -> (mu_zx, log_t_zx) ----------------
__global__ __launch_bounds__(128, 1) void enc_kernel(
    const float* __restrict__ x,
    const float* __restrict__ We1, const float* __restrict__ be1,
    const float* __restrict__ We2, const float* __restrict__ be2,
    const float* __restrict__ Wmu, const float* __restrict__ bmu,
    const float* __restrict__ Wlt, const float* __restrict__ blt,
    const float* __restrict__ b_muz, const float* __restrict__ b_ltz,
    float* __restrict__ out)
{
  const int tid = threadIdx.x;
  const int w   = tid >> 6;           // wave 0/1
  const int pb  = tid & 63;           // point within block
  const int p   = blockIdx.x * 64 + pb;
  const int ob  = __builtin_amdgcn_readfirstlane(w * 50);

  const float x0 = x[p*3+0], x1 = x[p*3+1], x2 = x[p*3+2];

  v2f acc2[25];
  #pragma unroll
  for (int i = 0; i < 25; ++i) { acc2[i].x = 0.f; acc2[i].y = 0.f; }

  for (int k = 0; k < HID; ++k) {
    float a   = fmaf(x0, We1[k], fmaf(x1, We1[HID+k], fmaf(x2, We1[2*HID+k], be1[k])));
    float sig = 1.f / (1.f + __expf(-a));
    float h1  = a * sig;
    const v2f hh = splat(h1);
    const v2f* row2 = (const v2f*)(We2 + k*HID + ob);
    #pragma unroll
    for (int oo = 0; oo < 25; ++oo) acc2[oo] = FMA2(hh, row2[oo], acc2[oo]);
  }

  float m0 = 0.f, m1 = 0.f, lt = 0.f;
  #pragma unroll
  for (int oo = 0; oo < 25; ++oo) {
    #pragma unroll
    for (int h = 0; h < 2; ++h) {
      const int o = ob + 2*oo + h;
      float a   = (h ? acc2[oo].y : acc2[oo].x) + be2[o];
      float sig = 1.f / (1.f + __expf(-a));
      float h2  = a * sig;
      m0 = fmaf(h2, Wmu[o*2+0], m0);
      m1 = fmaf(h2, Wmu[o*2+1], m1);
      lt = fmaf(h2, Wlt[o],     lt);
    }
  }

  __shared__ float red[2][64][3];
  red[w][pb][0] = m0; red[w][pb][1] = m1; red[w][pb][2] = lt;
  __syncthreads();
  if (w == 0) {
    m0 += red[1][pb][0] + bmu[0];
    m1 += red[1][pb][1] + bmu[1];
    lt += red[1][pb][2] + blt[0];
    out[OFF_MUZX + p*2+0] = m0;
    out[OFF_MUZX + p*2+1] = m1;
    out[OFF_LTZX + p]     = lt;
    out[OFF_MUZ  + p*2+0] = b_muz[0];
    out[OFF_MUZ  + p*2+1] = b_muz[1];
    out[OFF_LTZ  + p]     = b_ltz[0];
  }
}

// ------------- SDE: 100 Euler-Maruyama steps on the pullback metric ----------
// Block = 64 threads = 1 wave = 16 points, 4 lanes per point, 25 j per lane.
// ALL decoder weights live in VGPRs (25 j x 9 floats = 225 regs): zero LDS,
// zero barriers in the kernel. At ~300 VGPR this is 1 wave/SIMD; the grid's
// 2048 waves run as 2 passes over the 1024 SIMDs. 30 independent accumulator
// chains provide the ILP to keep the VALU issuing at 1 wave/SIMD.
// Noise is software-prefetched one step ahead (HBM latency ~900 cyc).
__global__ __launch_bounds__(64, 1) void sde_kernel(
    const float* __restrict__ Wd1,  const float* __restrict__ bd1,
    const float* __restrict__ Wdmu, const float* __restrict__ bdmu,
    const float* __restrict__ Wds,  const float* __restrict__ bds,
    const float* __restrict__ noise,
    float* __restrict__ out)
{
  const int tid   = threadIdx.x;
  const int l     = tid & 3;                    // lane within quad
  const int p     = blockIdx.x * 16 + (tid >> 2);
  const int jbase = l * 25;

  // ---- load this lane's 25 weight records into registers (L2-broadcast) ----
  float W0r[25], W1r[25], br[25], m0r[25], m1r[25], m2r[25], s0r[25], s1r[25], s2r[25];
  #pragma unroll
  for (int jj = 0; jj < 25; ++jj) {
    const int j = jbase + jj;
    W0r[jj] = Wd1[j];
    W1r[jj] = Wd1[HID + j];
    br [jj] = bd1[j];
    m0r[jj] = Wdmu[j*3+0];  m1r[jj] = Wdmu[j*3+1];  m2r[jj] = Wdmu[j*3+2];
    s0r[jj] = Wds [j*3+0];  s1r[jj] = Wds [j*3+1];  s2r[jj] = Wds [j*3+2];
  }

  float z0 = out[OFF_MUZX + p*2+0];
  float z1 = out[OFF_MUZX + p*2+1];
  const float sdt = __expf(out[OFF_LTZX + p]) * 0.1f;  // sqrt(dt) = exp(lt)/sqrt(100)

  const float2* __restrict__ noise2 = (const float2*)noise;
  float2 nz = noise2[p];                                // step 0 noise

  for (int step = 0; step < STEPS; ++step) {
    // prefetch next step's noise; latency hides under the j-loop
    const int nstep = (step + 1 < STEPS) ? step + 1 : step;
    const float2 nz_next = noise2[(size_t)nstep*N_PTS + p];

    float Jm[3][2] = {}, Js[3][2] = {}, Km[3][3] = {}, Ks[3][3] = {};
    #pragma unroll
    for (int jj = 0; jj < 25; ++jj) {
      const float W0 = W0r[jj], W1 = W1r[jj];
      float a   = fmaf(z0, W0, fmaf(z1, W1, br[jj]));
      float e   = __expf(-a);
      float sig = __builtin_amdgcn_rcpf(1.f + e);
      float t1  = 1.f - sig;
      float pp  = sig * t1;
      float u   = fmaf(a, pp, sig);                          // swish'
      float u2  = pp * fmaf(a, fmaf(-2.f, sig, 1.f), 2.f);   // swish''
      float c0  = u*W0,  c1  = u*W1;
      float r0  = u2*W0, r1  = u2*W1;
      float q00 = r0*W0, q01 = r0*W1, q11 = r1*W1;
      const float mw[3] = {m0r[jj], m1r[jj], m2r[jj]};
      const float sw[3] = {s0r[jj], s1r[jj], s2r[jj]};
      #pragma unroll
      for (int o = 0; o < 3; ++o) {
        Jm[o][0] = fmaf(mw[o], c0,  Jm[o][0]);
        Jm[o][1] = fmaf(mw[o], c1,  Jm[o][1]);
        Js[o][0] = fmaf(sw[o], c0,  Js[o][0]);
        Js[o][1] = fmaf(sw[o], c1,  Js[o][1]);
        Km[o][0] = fmaf(mw[o], q00, Km[o][0]);
        Km[o][1] = fmaf(mw[o], q01, Km[o][1]);
        Km[o][2] = fmaf(mw[o], q11, Km[o][2]);
        Ks[o][0] = fmaf(sw[o], q00, Ks[o][0]);
        Ks[o][1] = fmaf(sw[o], q01, Ks[o][1]);
        Ks[o][2] = fmaf(sw[o], q11, Ks[o][2]);
      }
    }
    // complete the j-sums across the quad (linear, so reduce before products)
    #pragma unroll
    for (int o = 0; o < 3; ++o) {
      Jm[o][0]=qreduce(Jm[o][0]); Jm[o][1]=qreduce(Jm[o][1]);
      Js[o][0]=qreduce(Js[o][0]); Js[o][1]=qreduce(Js[o][1]);
      Km[o][0]=qreduce(Km[o][0]); Km[o][1]=qreduce(Km[o][1]); Km[o][2]=qreduce(Km[o][2]);
      Ks[o][0]=qreduce(Ks[o][0]); Ks[o][1]=qreduce(Ks[o][1]); Ks[o][2]=qreduce(Ks[o][2]);
    }

    // G = J^T J (2x2 sym)
    float G00=0.f, G01=0.f, G11=0.f;
    #pragma unroll
    for (int o = 0; o < 3; ++o) {
      G00 += Jm[o][0]*Jm[o][0] + Js[o][0]*Js[o][0];
      G01 += Jm[o][0]*Jm[o][1] + Js[o][0]*Js[o][1];
      G11 += Jm[o][1]*Jm[o][1] + Js[o][1]*Js[o][1];
    }
    // D[c][l] = dG[km]/dz_l (sym in k,m)
    float D00=0.f, D01=0.f, D10=0.f, D11=0.f, D20=0.f, D21=0.f;
    #pragma unroll
    for (int o = 0; o < 3; ++o) {
      D00 += 2.f*(Km[o][0]*Jm[o][0] + Ks[o][0]*Js[o][0]);
      D01 += 2.f*(Km[o][1]*Jm[o][0] + Ks[o][1]*Js[o][0]);
      D10 += Km[o][0]*Jm[o][1] + Jm[o][0]*Km[o][1] + Ks[o][0]*Js[o][1] + Js[o][0]*Ks[o][1];
      D11 += Km[o][1]*Jm[o][1] + Jm[o][0]*Km[o][2] + Ks[o][1]*Js[o][1] + Js[o][0]*Ks[o][2];
      D20 += 2.f*(Km[o][1]*Jm[o][1] + Ks[o][1]*Js[o][1]);
      D21 += 2.f*(Km[o][2]*Jm[o][1] + Ks[o][2]*Js[o][1]);
    }
    const float det = fmaf(G00, G11, -G01*G01);
    const float id  = __builtin_amdgcn_rcpf(det);
    const float i00 = G11*id, i01 = -G01*id, i11 = G00*id;
    // T[k,l,m] = Dg[k,m,l] + Dg[l,m,k] - Dg[k,l,m]
    const float T000 = D00;
    const float T001 = 2.f*D10 - D01;
    const float T010 = D01;
    const float T011 = D20;
    const float T110 = 2.f*D11 - D20;
    const float T111 = D21;
    // Chris[i][c] = 0.5 * ginv[i,m] T[k,l,m]
    const float C00 = 0.5f*(i00*T000 + i01*T001);
    const float C01 = 0.5f*(i00*T010 + i01*T011);
    const float C02 = 0.5f*(i00*T110 + i01*T111);
    const float C10 = 0.5f*(i01*T000 + i11*T001);
    const float C11 = 0.5f*(i01*T010 + i11*T011);
    const float C12 = 0.5f*(i01*T110 + i11*T111);
    // drift[i] = 0.5 * ginv[j,k] Chris[i,j,k]
    const float dr0 = 0.5f*(i00*C00 + 2.f*i01*C01 + i11*C02);
    const float dr1 = 0.5f*(i00*C10 + 2.f*i01*C11 + i11*C12);

    const float dw0 = sdt*nz.x, dw1 = sdt*nz.y;
    z0 += dr0 + i00*dw0 + i01*dw1;   // + ginv @ dW
    z1 += dr1 + i01*dw0 + i11*dw1;
    nz = nz_next;
  }

  // ---- final decode on z ----
  float macc[3] = {}, sacc[3] = {};
  #pragma unroll
  for (int jj = 0; jj < 25; ++jj) {
    const float W0 = W0r[jj], W1 = W1r[jj];
    float a   = fmaf(z0, W0, fmaf(z1, W1, br[jj]));
    float sig = __builtin_amdgcn_rcpf(1.f + __expf(-a));
    float h   = a * sig;
    macc[0] = fmaf(h, m0r[jj], macc[0]);
    macc[1] = fmaf(h, m1r[jj], macc[1]);
    macc[2] = fmaf(h, m2r[jj], macc[2]);
    sacc[0] = fmaf(h, s0r[jj], sacc[0]);
    sacc[1] = fmaf(h, s1r[jj], sacc[1]);
    sacc[2] = fmaf(h, s2r[jj], sacc[2]);
  }
  #pragma unroll
  for (int o = 0; o < 3; ++o) { macc[o] = qreduce(macc[o]); sacc[o] = qreduce(sacc[o]); }

  if (l == 0) {
    out[OFF_Z + p*2+0] = z0;
    out[OFF_Z + p*2+1] = z1;
    #pragma unroll
    for (int o = 0; o < 3; ++o) {
      out[OFF_MUXZ + p*3 + o] = macc[o] + bdmu[o];
      out[OFF_LSXZ + p*3 + o] = sacc[o] + bds[o];
    }
  }
}

extern "C" void kernel_launch(void* const* d_in, const int* in_sizes, int n_in,
                              void* d_out, int out_size, void* d_ws, size_t ws_size,
                              hipStream_t stream) {
  (void)in_sizes; (void)n_in; (void)d_ws; (void)ws_size; (void)out_size;
  const float* x    = (const float*)d_in[0];
  const float* We1  = (const float*)d_in[1];
  const float* be1  = (const float*)d_in[2];
  const float* We2  = (const float*)d_in[3];
  const float* be2  = (const float*)d_in[4];
  const float* Wmu  = (const float*)d_in[5];
  const float* bmu  = (const float*)d_in[6];
  const float* Wlt  = (const float*)d_in[7];
  const float* blt  = (const float*)d_in[8];
  const float* Wd1  = (const float*)d_in[9];
  const float* bd1  = (const float*)d_in[10];
  const float* Wdmu = (const float*)d_in[11];
  const float* bdmu = (const float*)d_in[12];
  const float* Wds  = (const float*)d_in[13];
  const float* bds  = (const float*)d_in[14];
  const float* bmz  = (const float*)d_in[15];
  const float* blz  = (const float*)d_in[16];
  const float* noise= (const float*)d_in[17];
  float* out = (float*)d_out;

  enc_kernel<<<512, 128, 0, stream>>>(x, We1, be1, We2, be2, Wmu, bmu, Wlt, blt,
                                      bmz, blz, out);
  sde_kernel<<<2048, 64, 0, stream>>>(Wd1, bd1, Wdmu, bdmu, Wds, bds, noise, out);
}